// Round 7
// baseline (1458.493 us; speedup 1.0000x reference)
//
#include <hip/hip_runtime.h>

#define EMBD 256
#define SEQL 512
#define NCOL 512
#define THR  512
#define NRING 64          // rings of 2 batch rows; 8 WGs (col-groups) per ring
#define RPW  2            // rows per ring

typedef unsigned int u32;
typedef unsigned long long u64;
typedef _Float16 h2 __attribute__((ext_vector_type(2)));

#define WS_W16_OFF 0
#define WS_X_OFF   (768 * 1024)
// X: u64[2 slots][NRING][RPW][256 pairs] = 512 KB. Each u64 = (tag32<<32)|(2 f16 cols)

static __device__ __forceinline__ float dot2(u32 a, u32 b, float c) {
#if __has_builtin(__builtin_amdgcn_fdot2)
    return __builtin_amdgcn_fdot2(__builtin_bit_cast(h2, a), __builtin_bit_cast(h2, b), c, false);
#else
    h2 ha = __builtin_bit_cast(h2, a), hb = __builtin_bit_cast(h2, b);
    float r = fmaf((float)ha.x, (float)hb.x, c);
    return fmaf((float)ha.y, (float)hb.y, r);
#endif
}

static __device__ __forceinline__ u32 packh2(float a, float b) {
    _Float16 lo = (_Float16)a, hi = (_Float16)b;
    return (u32)__builtin_bit_cast(unsigned short, lo)
         | ((u32)__builtin_bit_cast(unsigned short, hi) << 16);
}

static __device__ __forceinline__ u32 bcast(u32 v, int l) {
    return (u32)__builtin_amdgcn_readlane((int)v, l);
}

// zero both X slots (65536 u64) -- clears stale tags from previous graph replays
__global__ __launch_bounds__(1024)
void init_X(u64* __restrict__ X) {
    X[(size_t)blockIdx.x * 1024 + threadIdx.x] = 0ull;
}

// W (f32 [768][512]) -> W16 (dword [384][512]): dword(kp,c) = (h(W[2kp][c]), h(W[2kp+1][c]))
__global__ __launch_bounds__(256)
void convert_W(const float* __restrict__ W, u32* __restrict__ W16) {
    int idx = blockIdx.x * 256 + threadIdx.x;
    if (idx >= 384 * NCOL) return;
    int kp = idx >> 9, c = idx & 511;
    float lo = W[(size_t)(2 * kp) * NCOL + c];
    float hi = W[(size_t)(2 * kp + 1) * NCOL + c];
    W16[idx] = packh2(lo, hi);
}

// 256 WGs x 512 thr. WG (pr,cg): rings 2pr,2pr+1 (rows pr*4..+3), cols [cg*64,+64).
// Wave wv = k-slice: emb pairs [wv*16,+16), state pairs [wv*32,+32) (producer cg'=wv).
// Broadcasts via v_readlane->SGPR feeding v_dot2 src0: NO LDS on the broadcast path.
// Exchange: tag-embedded u64 (seqlock-free), depth-2 slots; own slice via 64-dword LDS.
__global__ __launch_bounds__(THR, 1)
void rnn_rl(const int*   __restrict__ tokens,
            const float* __restrict__ V,
            const u32*   __restrict__ W16,
            const float* __restrict__ bias,
            const float* __restrict__ Wd,
            const float* __restrict__ bd,
            float*       __restrict__ y,
            u64*         __restrict__ X)
{
    __shared__ float partA[RPW][64][9];
    __shared__ float partB[RPW][64][9];
    __shared__ int   toks[4][SEQL];
    __shared__ u32   own[2][64];      // this WG's fresh slice: [ring][row*32+pair]
    __shared__ float yr[8][4];

    const int tid   = threadIdx.x;
    const int wg    = blockIdx.x;
    const int pr    = wg >> 3;
    const int cg    = wg & 7;
    const int ringA = 2 * pr;
    const int wv    = tid >> 6;
    const int lane  = tid & 63;
    const int gc    = cg * 64 + lane;
    const int row0  = pr * 4;

    for (int i = tid; i < 4 * SEQL; i += THR)
        toks[i >> 9][i & 511] = tokens[(row0 + (i >> 9)) * SEQL + (i & 511)];
    if (tid < 128) own[tid >> 6][tid & 63] = 0u;

    u32 we[16], ws[32];
    #pragma unroll
    for (int i = 0; i < 16; ++i) we[i] = W16[(size_t)(wv * 16 + i) * NCOL + gc];
    #pragma unroll
    for (int j = 0; j < 32; ++j) ws[j] = W16[(size_t)(128 + wv * 32 + j) * NCOL + gc];

    __syncthreads();

    // emb role: lane -> (row erow, pair gpair) within this wave's 16-pair slice
    const int erow  = lane >> 4;
    const int gpair = wv * 16 + (lane & 15);
    u32 em;
    {
        int tok = toks[erow][0];
        float2 e0 = *(const float2*)&V[(size_t)tok * EMBD + 2 * gpair];
        em = packh2(e0.x, e0.y);
    }

    const float bias_r = (tid < 256) ? bias[cg * 64 + (tid & 63)] : 0.f;
    const int  lrow = lane >> 5, lpair = lane & 31;
    const bool ownwv = (wv == cg);
    const int  ringsel = tid >> 7, rrow = (tid >> 6) & 1, rcol = tid & 63;

    for (int t = 0; t < SEQL; ++t) {
        // ---- speculative exchange loads: state(t-1), tag t, slot (t+1)&1 ----
        const u64* XA = X + (((size_t)((t + 1) & 1) * NRING + ringA    ) * RPW + lrow) * 256 + wv * 32 + lpair;
        const u64* XB = X + (((size_t)((t + 1) & 1) * NRING + ringA + 1) * RPW + lrow) * 256 + wv * 32 + lpair;
        u64 vA = 0, vB = 0;
        if (!ownwv) {
            vA = __hip_atomic_load(XA, __ATOMIC_RELAXED, __HIP_MEMORY_SCOPE_AGENT);
            vB = __hip_atomic_load(XB, __ATOMIC_RELAXED, __HIP_MEMORY_SCOPE_AGENT);
        }

        // emb(t+1) prefetch (per-lane, no LDS)
        const int tn   = (t + 1 < SEQL) ? (t + 1) : (SEQL - 1);
        const int tokn = toks[erow][tn];
        const float2 ev = *(const float2*)&V[(size_t)tokn * EMBD + 2 * gpair];

        // ---- E phase: emb part, 4 rows x 16 pairs (readlane broadcasts) ----
        float a0 = 0.f, a1 = 0.f, b0 = 0.f, b1 = 0.f;
        #pragma unroll
        for (int j = 0; j < 16; ++j) {
            a0 = dot2(bcast(em,      j), we[j], a0);
            a1 = dot2(bcast(em, 16 + j), we[j], a1);
            b0 = dot2(bcast(em, 32 + j), we[j], b0);
            b1 = dot2(bcast(em, 48 + j), we[j], b1);
        }

        // ---- ring A: validate + state matvec ----
        u32 sA;
        if (ownwv) {
            sA = own[0][lane];
        } else {
            if (!__all((u32)(vA >> 32) == (u32)t)) {
                do {
                    __builtin_amdgcn_s_sleep(1);
                    vA = __hip_atomic_load(XA, __ATOMIC_RELAXED, __HIP_MEMORY_SCOPE_AGENT);
                } while (!__all((u32)(vA >> 32) == (u32)t));
            }
            sA = (u32)vA;
        }
        #pragma unroll
        for (int p = 0; p < 32; ++p) {
            a0 = dot2(bcast(sA,      p), ws[p], a0);
            a1 = dot2(bcast(sA, 32 + p), ws[p], a1);
        }

        // ---- ring B: validate + state matvec ----
        u32 sB;
        if (ownwv) {
            sB = own[1][lane];
        } else {
            if (!__all((u32)(vB >> 32) == (u32)t)) {
                do {
                    __builtin_amdgcn_s_sleep(1);
                    vB = __hip_atomic_load(XB, __ATOMIC_RELAXED, __HIP_MEMORY_SCOPE_AGENT);
                } while (!__all((u32)(vB >> 32) == (u32)t));
            }
            sB = (u32)vB;
        }
        #pragma unroll
        for (int p = 0; p < 32; ++p) {
            b0 = dot2(bcast(sB,      p), ws[p], b0);
            b1 = dot2(bcast(sB, 32 + p), ws[p], b1);
        }

        partA[0][lane][wv] = a0;
        partA[1][lane][wv] = a1;
        partB[0][lane][wv] = b0;
        partB[1][lane][wv] = b1;
        __syncthreads();   // B1: partials visible; own[] reads of step t done

        // ---- reduce + tanh + publish (tagged u64 store; own slice -> LDS) ----
        if (tid < 256) {
            const float* P = ringsel ? &partB[rrow][rcol][0] : &partA[rrow][rcol][0];
            float s = P[0] + P[1] + P[2] + P[3] + P[4] + P[5] + P[6] + P[7] + bias_r;
            s = tanhf(s);
            float snb = __shfl_down(s, 1);
            if ((rcol & 1) == 0) {
                u32 dw = packh2(s, snb);
                const int lp = rcol >> 1;
                own[ringsel][rrow * 32 + lp] = dw;
                u64 pk = (u64)dw | ((u64)(u32)(t + 1) << 32);
                u64* dst = X + (((size_t)(t & 1) * NRING + ringA + ringsel) * RPW + rrow) * 256 + cg * 32 + lp;
                __hip_atomic_store(dst, pk, __ATOMIC_RELAXED, __HIP_MEMORY_SCOPE_AGENT);
            }
        }
        em = packh2(ev.x, ev.y);   // emb(t+1) stays in-register
        __syncthreads();   // B2: own[] + next-step visibility
    }

    // ---- epilogue: cg==0 gathers state(511) (slot 1, tag SEQL) and computes y ----
    if (cg == 0) {
        u32 dA, dB;
        if (ownwv) {   // wv == 0
            dA = own[0][lane];
            dB = own[1][lane];
        } else {
            const u64* XA = X + (((size_t)1 * NRING + ringA    ) * RPW + lrow) * 256 + wv * 32 + lpair;
            const u64* XB = X + (((size_t)1 * NRING + ringA + 1) * RPW + lrow) * 256 + wv * 32 + lpair;
            u64 vA, vB;
            do {
                vA = __hip_atomic_load(XA, __ATOMIC_RELAXED, __HIP_MEMORY_SCOPE_AGENT);
            } while (!__all((u32)(vA >> 32) == (u32)SEQL));
            do {
                vB = __hip_atomic_load(XB, __ATOMIC_RELAXED, __HIP_MEMORY_SCOPE_AGENT);
            } while (!__all((u32)(vB >> 32) == (u32)SEQL));
            dA = (u32)vA;
            dB = (u32)vB;
        }
        const int h = 2 * (wv * 32 + lpair);
        const float2 wd = *(const float2*)&Wd[h];
        h2 ha = __builtin_bit_cast(h2, dA);
        h2 hb = __builtin_bit_cast(h2, dB);
        float pA = (float)ha.x * wd.x + (float)ha.y * wd.y;   // ring A, row lrow
        float pB = (float)hb.x * wd.x + (float)hb.y * wd.y;   // ring B, row lrow
        #pragma unroll
        for (int off = 16; off > 0; off >>= 1) {
            pA += __shfl_down(pA, off, 32);
            pB += __shfl_down(pB, off, 32);
        }
        if (lane == 0)  { yr[wv][0] = pA; yr[wv][2] = pB; }
        if (lane == 32) { yr[wv][1] = pA; yr[wv][3] = pB; }
        __syncthreads();
        if (tid < 4) {
            float s = 0.f;
            #pragma unroll
            for (int w = 0; w < 8; ++w) s += yr[w][tid];
            y[row0 + tid] = s + bd[0];
        }
    }
}

extern "C" void kernel_launch(void* const* d_in, const int* in_sizes, int n_in,
                              void* d_out, int out_size, void* d_ws, size_t ws_size,
                              hipStream_t stream)
{
    const int*   tokens = (const int*)  d_in[0];
    const float* V      = (const float*)d_in[1];
    const float* W      = (const float*)d_in[2];
    const float* b      = (const float*)d_in[3];
    const float* Wd     = (const float*)d_in[4];
    const float* bd     = (const float*)d_in[5];
    float* y = (float*)d_out;

    u32* W16 = (u32*)((char*)d_ws + WS_W16_OFF);
    u64* X   = (u64*)((char*)d_ws + WS_X_OFF);

    hipLaunchKernelGGL(init_X, dim3(64), dim3(1024), 0, stream, X);
    hipLaunchKernelGGL(convert_W, dim3((384 * NCOL + 255) / 256), dim3(256), 0, stream, W, W16);
    hipLaunchKernelGGL(rnn_rl, dim3(256), dim3(THR), 0, stream,
                       tokens, V, W16, b, Wd, bd, y, X);
}